// Round 1
// baseline (122.627 us; speedup 1.0000x reference)
//
#include <hip/hip_runtime.h>
#include <math.h>

#define HDIM 5
#define GATES 20      // 4*H
#define DDIM 32
#define EDIM 32
#define INDIM 128     // D + 3E
#define VOC 10
#define SPN (3 * VOC * GATES)   // 600 floats: embedding->gate tables

__device__ __forceinline__ float sigmoidf_(float x) {
    // 1/(1+e^-x); rcp(inf)=0 handles saturation
    return __builtin_amdgcn_rcpf(1.0f + __expf(-x));
}
__device__ __forceinline__ float tanhf_(float x) {
    // tanh(x) = 2/(1+e^-2x) - 1
    float e = __expf(-2.0f * x);
    return fmaf(2.0f, __builtin_amdgcn_rcpf(1.0f + e), -1.0f);
}

// Single fused kernel: no workspace, no second dispatch.
// Each block recomputes the tiny emb->gate table (600 dots of len 32,
// ~75 FMA/thread) in LDS; each thread recomputes its own hh0/hh1
// (bias + h @ W_hh^T, 200 FMA) instead of reading them back from ws.
__global__ __launch_bounds__(256, 4) void decoder_fused(
    const float* __restrict__ hidden,   // [2,B,H]
    const float* __restrict__ cell,     // [2,B,H]
    const float* __restrict__ dec_x,    // [T,B,D]
    const int*   __restrict__ midc,     // [T,B]
    const int*   __restrict__ ftc,      // [T,B]
    const int*   __restrict__ mfc,      // [T,B]
    const float* __restrict__ emb,      // [V,E]
    const float* __restrict__ W_ih0,    // [20,128]
    const float* __restrict__ W_hh0,    // [20,5]
    const float* __restrict__ b_ih0,
    const float* __restrict__ b_hh0,
    const float* __restrict__ W_ih1,    // [20,5]
    const float* __restrict__ W_hh1,    // [20,5]
    const float* __restrict__ b_ih1,
    const float* __restrict__ b_hh1,
    float* __restrict__ out,            // [horizon,B,H]
    int B, int total)
{
    __shared__ float sP[SPN];
    // Cooperative in-block build of the embedding->gate dot tables.
    for (int j = threadIdx.x; j < SPN; j += 256) {
        int s = j / (VOC * GATES);
        int rem = j - s * (VOC * GATES);
        int v = rem / GATES, r = rem - v * GATES;
        const float4* ev = (const float4*)(emb + v * EDIM);
        const float4* wv = (const float4*)(W_ih0 + r * INDIM + DDIM + s * EDIM);
        float a = 0.0f;
        #pragma unroll
        for (int k = 0; k < EDIM / 4; ++k) {
            float4 e4 = ev[k], w4 = wv[k];
            a = fmaf(e4.x, w4.x, a); a = fmaf(e4.y, w4.y, a);
            a = fmaf(e4.z, w4.z, a); a = fmaf(e4.w, w4.w, a);
        }
        sP[j] = a;
    }
    __syncthreads();

    const int idx = blockIdx.x * 256 + threadIdx.x;   // idx = t*B + b
    if (idx >= total) return;
    const int b = (int)((unsigned)idx % (unsigned)B);

    // Issue the long-latency loads up front.
    const float4* xp = (const float4*)dec_x + (size_t)idx * (DDIM / 4);
    float4 x[DDIM / 4];
    #pragma unroll
    for (int k = 0; k < DDIM / 4; ++k) x[k] = xp[k];
    const int vm = midc[idx], vf = ftc[idx], vmf = mfc[idx];

    float h0[HDIM];
    #pragma unroll
    for (int h = 0; h < HDIM; ++h) h0[h] = hidden[(size_t)b * HDIM + h];

    // acc = b_ih0 + b_hh0 + h0 @ W_hh0^T  (weights/biases wave-uniform -> scalar pipe)
    float acc[GATES];
    #pragma unroll
    for (int r = 0; r < GATES; ++r) {
        float a = b_ih0[r] + b_hh0[r];
        #pragma unroll
        for (int h = 0; h < HDIM; ++h) a = fmaf(h0[h], W_hh0[r * HDIM + h], a);
        acc[r] = a;
    }

    // acc += embedding->gate table entries (LDS gather; rows 80B apart, 16B aligned)
    const float4* P0 = (const float4*)(sP + vm * GATES);
    const float4* P1 = (const float4*)(sP + VOC * GATES + vf * GATES);
    const float4* P2 = (const float4*)(sP + 2 * VOC * GATES + vmf * GATES);
    #pragma unroll
    for (int k = 0; k < 5; ++k) {
        float4 p0 = P0[k], p1 = P1[k], p2 = P2[k];
        acc[4 * k + 0] += p0.x + p1.x + p2.x;
        acc[4 * k + 1] += p0.y + p1.y + p2.y;
        acc[4 * k + 2] += p0.z + p1.z + p2.z;
        acc[4 * k + 3] += p0.w + p1.w + p2.w;
    }

    // acc += dec_x[t,b,:] @ W_ih0[:, :32]^T   (weights via scalar pipe)
    #pragma unroll
    for (int r = 0; r < GATES; ++r) {
        const float* w = W_ih0 + r * INDIM;   // wave-uniform -> s_load
        float a = acc[r];
        #pragma unroll
        for (int k = 0; k < DDIM / 4; ++k) {
            a = fmaf(x[k].x, w[4 * k + 0], a);
            a = fmaf(x[k].y, w[4 * k + 1], a);
            a = fmaf(x[k].z, w[4 * k + 2], a);
            a = fmaf(x[k].w, w[4 * k + 3], a);
        }
        acc[r] = a;
    }

    // layer-0 nonlinearity -> h1
    float h1[HDIM];
    #pragma unroll
    for (int r = 0; r < HDIM; ++r) {
        float c0 = cell[(size_t)b * HDIM + r];
        float ii = sigmoidf_(acc[r]);
        float ff = sigmoidf_(acc[HDIM + r]);
        float gg = tanhf_(acc[2 * HDIM + r]);
        float oo = sigmoidf_(acc[3 * HDIM + r]);
        float cn = fmaf(ff, c0, ii * gg);
        h1[r] = oo * tanhf_(cn);
    }

    // layer-1 gates: g1 = b_ih1 + b_hh1 + h1v @ W_hh1^T + h1 @ W_ih1^T
    // (h1v loaded late to keep register pressure down during the big x-loop)
    float h1v[HDIM];
    #pragma unroll
    for (int h = 0; h < HDIM; ++h) h1v[h] = hidden[((size_t)B + b) * HDIM + h];
    float g1[GATES];
    #pragma unroll
    for (int r = 0; r < GATES; ++r) {
        float a = b_ih1[r] + b_hh1[r];
        #pragma unroll
        for (int h = 0; h < HDIM; ++h)
            a = fmaf(h1v[h], W_hh1[r * HDIM + h], a);  // uniform -> s_load
        #pragma unroll
        for (int h = 0; h < HDIM; ++h)
            a = fmaf(h1[h], W_ih1[r * HDIM + h], a);   // uniform -> s_load
        g1[r] = a;
    }

    // layer-1 nonlinearity -> out
    #pragma unroll
    for (int r = 0; r < HDIM; ++r) {
        float c1 = cell[((size_t)B + b) * HDIM + r];
        float ii = sigmoidf_(g1[r]);
        float ff = sigmoidf_(g1[HDIM + r]);
        float gg = tanhf_(g1[2 * HDIM + r]);
        float oo = sigmoidf_(g1[3 * HDIM + r]);
        float cn = fmaf(ff, c1, ii * gg);
        out[(size_t)idx * HDIM + r] = oo * tanhf_(cn);
    }
}

extern "C" void kernel_launch(void* const* d_in, const int* in_sizes, int n_in,
                              void* d_out, int out_size, void* d_ws, size_t ws_size,
                              hipStream_t stream) {
    // dict order: horizon, hidden, cell, dec_x, mote_id_cat, fault_type_cat,
    // mote_fault_cat, mote_embed, W_ih0, W_hh0, b_ih0, b_hh0, W_ih1, W_hh1, b_ih1, b_hh1
    const float* hidden = (const float*)d_in[1];
    const float* cellp  = (const float*)d_in[2];
    const float* dec_x  = (const float*)d_in[3];
    const int*   midc   = (const int*)d_in[4];
    const int*   ftc    = (const int*)d_in[5];
    const int*   mfc    = (const int*)d_in[6];
    const float* emb    = (const float*)d_in[7];
    const float* W_ih0  = (const float*)d_in[8];
    const float* W_hh0  = (const float*)d_in[9];
    const float* b_ih0  = (const float*)d_in[10];
    const float* b_hh0  = (const float*)d_in[11];
    const float* W_ih1  = (const float*)d_in[12];
    const float* W_hh1  = (const float*)d_in[13];
    const float* b_ih1  = (const float*)d_in[14];
    const float* b_hh1  = (const float*)d_in[15];
    float* out = (float*)d_out;
    (void)d_ws; (void)ws_size;   // workspace intentionally unused

    int B = in_sizes[1] / (2 * HDIM);        // hidden is [2,B,H]
    int horizon = out_size / (B * HDIM);     // out is [horizon,B,H]
    int total = horizon * B;

    int grid = (total + 255) / 256;
    if (grid < 1) grid = 1;
    decoder_fused<<<grid, 256, 0, stream>>>(
        hidden, cellp, dec_x, midc, ftc, mfc, emb,
        W_ih0, W_hh0, b_ih0, b_hh0, W_ih1, W_hh1, b_ih1, b_hh1,
        out, B, total);
}

// Round 2
// 118.719 us; speedup vs baseline: 1.0329x; 1.0329x over previous
//
#include <hip/hip_runtime.h>
#include <math.h>

#define HDIM 5
#define GATES 20      // 4*H
#define DDIM 32
#define EDIM 32
#define INDIM 128     // D + 3E
#define VOC 10
#define SPN (3 * VOC * GATES)   // 600 floats: embedding->gate tables
#define HH_OFF 1024             // float offset of hh tables in ws

__device__ __forceinline__ float sigmoidf_(float x) {
    // 1/(1+e^-x); rcp(inf)=0 handles saturation
    return __builtin_amdgcn_rcpf(1.0f + __expf(-x));
}
__device__ __forceinline__ float tanhf_(float x) {
    // tanh(x) = 2/(1+e^-2x) - 1
    float e = __expf(-2.0f * x);
    return fmaf(2.0f, __builtin_amdgcn_rcpf(1.0f + e), -1.0f);
}

// One small dispatch: sP[600] = emb->gate dot tables; hh[2][B][20] = bias + h@W_hh^T.
// Amortizes the per-b recurrent-weight work ONCE (16 blocks) instead of per
// (t,b) thread — fused recompute measured 4 us slower (R1 post-mortem).
__global__ __launch_bounds__(256) void precompute_kernel(
    const float* __restrict__ hidden,   // [2,B,H]
    const float* __restrict__ emb,      // [V,E]
    const float* __restrict__ W_ih0,    // [20,128]
    const float* __restrict__ W_hh0, const float* __restrict__ b_ih0,
    const float* __restrict__ b_hh0,
    const float* __restrict__ W_hh1, const float* __restrict__ b_ih1,
    const float* __restrict__ b_hh1,
    float* __restrict__ ws, int B)
{
    int gid = blockIdx.x * 256 + threadIdx.x;
    if (gid < SPN) {
        int s = gid / (VOC * GATES);
        int rem = gid % (VOC * GATES);
        int v = rem / GATES, r = rem % GATES;
        const float4* ev = (const float4*)(emb + v * EDIM);
        const float4* wv = (const float4*)(W_ih0 + r * INDIM + DDIM + s * EDIM);
        float a = 0.0f;
        #pragma unroll
        for (int k = 0; k < EDIM / 4; ++k) {
            float4 e4 = ev[k], w4 = wv[k];
            a = fmaf(e4.x, w4.x, a); a = fmaf(e4.y, w4.y, a);
            a = fmaf(e4.z, w4.z, a); a = fmaf(e4.w, w4.w, a);
        }
        ws[gid] = a;
    }
    if (gid < B) {
        float h0[HDIM], h1v[HDIM];
        #pragma unroll
        for (int h = 0; h < HDIM; ++h) {
            h0[h]  = hidden[(size_t)gid * HDIM + h];
            h1v[h] = hidden[((size_t)B + gid) * HDIM + h];
        }
        #pragma unroll
        for (int r = 0; r < GATES; ++r) {
            float a0 = b_ih0[r] + b_hh0[r];
            float a1 = b_ih1[r] + b_hh1[r];
            #pragma unroll
            for (int h = 0; h < HDIM; ++h) {
                a0 = fmaf(h0[h],  W_hh0[r * HDIM + h], a0);
                a1 = fmaf(h1v[h], W_hh1[r * HDIM + h], a1);
            }
            ws[HH_OFF + (size_t)gid * GATES + r] = a0;
            ws[HH_OFF + (size_t)(B + gid) * GATES + r] = a1;
        }
    }
}

__global__ __launch_bounds__(256, 4) void decoder_kernel(
    const float* __restrict__ cell,     // [2,B,H]
    const float* __restrict__ dec_x,    // [T,B,D]
    const int*   __restrict__ midc,     // [T,B]
    const int*   __restrict__ ftc,      // [T,B]
    const int*   __restrict__ mfc,      // [T,B]
    const float* __restrict__ W_ih0,    // [20,128] (only cols 0..31 used here)
    const float* __restrict__ W_ih1,    // [20,5]
    const float* __restrict__ ws,       // sP + hh tables
    float* __restrict__ out,            // [horizon,B,H]
    int B, int total)
{
    __shared__ float sP[SPN];
    for (int j = threadIdx.x; j < SPN; j += 256) sP[j] = ws[j];
    __syncthreads();

    const int idx = blockIdx.x * 256 + threadIdx.x;   // idx = t*B + b
    if (idx >= total) return;
    const int t = idx / B;
    const int b = idx - t * B;
    (void)t;

    // Issue the long-latency loads up front.
    const float4* xp = (const float4*)dec_x + (size_t)idx * (DDIM / 4);
    float4 x[DDIM / 4];
    #pragma unroll
    for (int k = 0; k < DDIM / 4; ++k) x[k] = xp[k];

    const int vm = midc[idx], vf = ftc[idx], vmf = mfc[idx];

    // Prefetch layer-0 cell state now: its L2 latency hides under the
    // 640-FMA x@W loop below instead of stalling the layer-0 nonlinearity.
    float c0[HDIM];
    #pragma unroll
    for (int r = 0; r < HDIM; ++r) c0[r] = cell[(size_t)b * HDIM + r];

    // acc = hh0[b]  (bias + h0@W_hh0^T, precomputed)
    float acc[GATES];
    const float4* hh0p = (const float4*)(ws + HH_OFF + (size_t)b * GATES);
    #pragma unroll
    for (int k = 0; k < 5; ++k) {
        float4 h4 = hh0p[k];
        acc[4 * k + 0] = h4.x; acc[4 * k + 1] = h4.y;
        acc[4 * k + 2] = h4.z; acc[4 * k + 3] = h4.w;
    }

    // acc += embedding->gate table entries (LDS gather; rows are 80B apart, 16B aligned)
    const float4* P0 = (const float4*)(sP + vm * GATES);
    const float4* P1 = (const float4*)(sP + VOC * GATES + vf * GATES);
    const float4* P2 = (const float4*)(sP + 2 * VOC * GATES + vmf * GATES);
    #pragma unroll
    for (int k = 0; k < 5; ++k) {
        float4 p0 = P0[k], p1 = P1[k], p2 = P2[k];
        acc[4 * k + 0] += p0.x + p1.x + p2.x;
        acc[4 * k + 1] += p0.y + p1.y + p2.y;
        acc[4 * k + 2] += p0.z + p1.z + p2.z;
        acc[4 * k + 3] += p0.w + p1.w + p2.w;
    }

    // acc += dec_x[t,b,:] @ W_ih0[:, :32]^T   (weights via scalar pipe)
    #pragma unroll
    for (int r = 0; r < GATES; ++r) {
        const float* w = W_ih0 + r * INDIM;   // wave-uniform -> s_load
        float a = acc[r];
        #pragma unroll
        for (int k = 0; k < DDIM / 4; ++k) {
            a = fmaf(x[k].x, w[4 * k + 0], a);
            a = fmaf(x[k].y, w[4 * k + 1], a);
            a = fmaf(x[k].z, w[4 * k + 2], a);
            a = fmaf(x[k].w, w[4 * k + 3], a);
        }
        acc[r] = a;
    }

    // Prefetch layer-1 cell state before the layer-0 transcendentals.
    float c1v[HDIM];
    #pragma unroll
    for (int r = 0; r < HDIM; ++r) c1v[r] = cell[((size_t)B + b) * HDIM + r];

    // layer-0 nonlinearity -> h1
    float h1[HDIM];
    #pragma unroll
    for (int r = 0; r < HDIM; ++r) {
        float ii = sigmoidf_(acc[r]);
        float ff = sigmoidf_(acc[HDIM + r]);
        float gg = tanhf_(acc[2 * HDIM + r]);
        float oo = sigmoidf_(acc[3 * HDIM + r]);
        float cn = fmaf(ff, c0[r], ii * gg);
        h1[r] = oo * tanhf_(cn);
    }

    // layer-1 gates: g1 = hh1[b] + h1 @ W_ih1^T
    float g1[GATES];
    const float4* hh1p = (const float4*)(ws + HH_OFF + (size_t)(B + b) * GATES);
    #pragma unroll
    for (int k = 0; k < 5; ++k) {
        float4 h4 = hh1p[k];
        g1[4 * k + 0] = h4.x; g1[4 * k + 1] = h4.y;
        g1[4 * k + 2] = h4.z; g1[4 * k + 3] = h4.w;
    }
    #pragma unroll
    for (int r = 0; r < GATES; ++r) {
        float a = g1[r];
        #pragma unroll
        for (int h = 0; h < HDIM; ++h)
            a = fmaf(h1[h], W_ih1[r * HDIM + h], a);   // uniform -> s_load
        g1[r] = a;
    }

    // layer-1 nonlinearity -> out
    #pragma unroll
    for (int r = 0; r < HDIM; ++r) {
        float ii = sigmoidf_(g1[r]);
        float ff = sigmoidf_(g1[HDIM + r]);
        float gg = tanhf_(g1[2 * HDIM + r]);
        float oo = sigmoidf_(g1[3 * HDIM + r]);
        float cn = fmaf(ff, c1v[r], ii * gg);
        out[(size_t)idx * HDIM + r] = oo * tanhf_(cn);
    }
}

extern "C" void kernel_launch(void* const* d_in, const int* in_sizes, int n_in,
                              void* d_out, int out_size, void* d_ws, size_t ws_size,
                              hipStream_t stream) {
    // dict order: horizon, hidden, cell, dec_x, mote_id_cat, fault_type_cat,
    // mote_fault_cat, mote_embed, W_ih0, W_hh0, b_ih0, b_hh0, W_ih1, W_hh1, b_ih1, b_hh1
    const float* hidden = (const float*)d_in[1];
    const float* cellp  = (const float*)d_in[2];
    const float* dec_x  = (const float*)d_in[3];
    const int*   midc   = (const int*)d_in[4];
    const int*   ftc    = (const int*)d_in[5];
    const int*   mfc    = (const int*)d_in[6];
    const float* emb    = (const float*)d_in[7];
    const float* W_ih0  = (const float*)d_in[8];
    const float* W_hh0  = (const float*)d_in[9];
    const float* b_ih0  = (const float*)d_in[10];
    const float* b_hh0  = (const float*)d_in[11];
    const float* W_ih1  = (const float*)d_in[12];
    const float* W_hh1  = (const float*)d_in[13];
    const float* b_ih1  = (const float*)d_in[14];
    const float* b_hh1  = (const float*)d_in[15];
    float* out = (float*)d_out;
    float* ws  = (float*)d_ws;

    int B = in_sizes[1] / (2 * HDIM);        // hidden is [2,B,H]
    int horizon = out_size / (B * HDIM);     // out is [horizon,B,H]
    int total = horizon * B;

    int pre_n = (B > SPN ? B : SPN);
    int pre_grid = (pre_n + 255) / 256;
    precompute_kernel<<<pre_grid, 256, 0, stream>>>(
        hidden, emb, W_ih0, W_hh0, b_ih0, b_hh0, W_hh1, b_ih1, b_hh1, ws, B);

    int grid = (total + 255) / 256;
    if (grid < 1) grid = 1;
    decoder_kernel<<<grid, 256, 0, stream>>>(
        cellp, dec_x, midc, ftc, mfc, W_ih0, W_ih1, ws, out, B, total);
}